// Round 1
// baseline (261.611 us; speedup 1.0000x reference)
//
#include <hip/hip_runtime.h>

typedef __attribute__((ext_vector_type(8))) short bf16x8;
typedef __attribute__((ext_vector_type(16))) float f32x16;

#define MFMA32 __builtin_amdgcn_mfma_f32_32x32x16_bf16

__device__ __forceinline__ unsigned short bf16r(float f){
  unsigned u = __builtin_bit_cast(unsigned, f);
  unsigned r = (u + 0x7FFFu + ((u >> 16) & 1u)) >> 16;
  return (unsigned short)r;
}
__device__ __forceinline__ unsigned bfpack2(float a, float b){
  unsigned ua = __builtin_bit_cast(unsigned, a);
  unsigned ub = __builtin_bit_cast(unsigned, b);
  unsigned ra = (ua + 0x7FFFu + ((ua >> 16) & 1u)) >> 16;
  unsigned rb = (ub + 0x7FFFu + ((ub >> 16) & 1u)) & 0xFFFF0000u;
  return (ra & 0xFFFFu) | rb;
}
__device__ __forceinline__ float bf2f(unsigned short h){
  unsigned u = ((unsigned)h) << 16;
  return __builtin_bit_cast(float, u);
}

// ---------------- weight transpose: W[k][n] f32 -> WT[n][k] bf16 (512x512, 4 mats)
__global__ __launch_bounds__(256) void wt_kernel(
    const float* __restrict__ W0, const float* __restrict__ W1,
    const float* __restrict__ W2, const float* __restrict__ W3,
    unsigned short* __restrict__ T0, unsigned short* __restrict__ T1,
    unsigned short* __restrict__ T2, unsigned short* __restrict__ T3)
{
  int z = blockIdx.z;
  const float* W = z==0?W0 : z==1?W1 : z==2?W2 : W3;
  unsigned short* T = z==0?T0 : z==1?T1 : z==2?T2 : T3;
  __shared__ float tile[64][68];
  int kb0 = blockIdx.x*64, nb0 = blockIdx.y*64;
  int tid = threadIdx.x;
#pragma unroll
  for (int i=0;i<4;++i){
    int c = tid + i*256; int r = c>>4, cc = (c&15)*4;
    *(float4*)&tile[r][cc] = *(const float4*)&W[(kb0+r)*512 + nb0 + cc];
  }
  __syncthreads();
#pragma unroll
  for (int i=0;i<4;++i){
    int c = tid + i*256; int o = c*4; int n = o>>6, kk = o&63;
    ushort4 pk;
    pk.x = bf16r(tile[kk+0][n]); pk.y = bf16r(tile[kk+1][n]);
    pk.z = bf16r(tile[kk+2][n]); pk.w = bf16r(tile[kk+3][n]);
    *(ushort4*)&T[(nb0+n)*512 + kb0 + kk] = pk;
  }
}

// ---------------- GEMM: C[m][n] = A(f32,[M x 512]) @ W via BT(bf16,[n][k]) + bias
// EPI 0: store bf16.  EPI 1: store f32 = relu(acc+bias) + resid.
template<int EPI>
__global__ __launch_bounds__(256,2) void gemm_bt(
    const float* __restrict__ A, const unsigned short* __restrict__ BT,
    const float* __restrict__ bias, void* __restrict__ Cout,
    const float* __restrict__ resid)
{
  __shared__ short As[128][72];
  __shared__ short Bs[128][72];
  int m0 = blockIdx.x*128, n0 = blockIdx.y*128;
  int tid = threadIdx.x;
  int lane = tid & 63, w = tid >> 6, l5 = lane & 31, hi = lane >> 5;
  int wr = w >> 1, wc = w & 1;
  f32x16 acc00, acc01, acc10, acc11;
#pragma unroll
  for (int i=0;i<16;++i){ acc00[i]=0.f; acc01[i]=0.f; acc10[i]=0.f; acc11[i]=0.f; }

  for (int kt=0; kt<8; ++kt){
    int k0 = kt*64;
    __syncthreads();
#pragma unroll
    for (int i=0;i<4;++i){
      int c = tid + i*256; int r = c>>3, cc = (c&7)*8;
      const float* src = &A[(m0+r)*512 + k0 + cc];
      float4 v0 = *(const float4*)src;
      float4 v1 = *(const float4*)(src+4);
      uint4 pk;
      pk.x = bfpack2(v0.x, v0.y); pk.y = bfpack2(v0.z, v0.w);
      pk.z = bfpack2(v1.x, v1.y); pk.w = bfpack2(v1.z, v1.w);
      *(uint4*)&As[r][cc] = pk;
    }
#pragma unroll
    for (int i=0;i<4;++i){
      int c = tid + i*256; int r = c>>3, cc = (c&7)*8;
      *(uint4*)&Bs[r][cc] = *(const uint4*)&BT[(n0+r)*512 + k0 + cc];
    }
    __syncthreads();
#pragma unroll
    for (int ks=0; ks<4; ++ks){
      bf16x8 a0 = *(const bf16x8*)&As[wr*64 + l5     ][ks*16 + hi*8];
      bf16x8 a1 = *(const bf16x8*)&As[wr*64 + 32 + l5][ks*16 + hi*8];
      bf16x8 b0 = *(const bf16x8*)&Bs[wc*64 + l5     ][ks*16 + hi*8];
      bf16x8 b1 = *(const bf16x8*)&Bs[wc*64 + 32 + l5][ks*16 + hi*8];
      acc00 = MFMA32(a0, b0, acc00, 0,0,0);
      acc01 = MFMA32(a0, b1, acc01, 0,0,0);
      acc10 = MFMA32(a1, b0, acc10, 0,0,0);
      acc11 = MFMA32(a1, b1, acc11, 0,0,0);
    }
  }
#pragma unroll
  for (int mt=0; mt<2; ++mt){
#pragma unroll
    for (int nt=0; nt<2; ++nt){
      const f32x16& acc = mt==0 ? (nt==0?acc00:acc01) : (nt==0?acc10:acc11);
      int n = n0 + wc*64 + nt*32 + l5;
      float bn = bias[n];
#pragma unroll
      for (int r=0;r<16;++r){
        int m = m0 + wr*64 + mt*32 + (r&3) + 8*(r>>2) + 4*hi;
        float v = acc[r] + bn;
        if (EPI==0){
          ((unsigned short*)Cout)[m*512 + n] = bf16r(v);
        } else {
          ((float*)Cout)[m*512 + n] = fmaxf(v, 0.f) + resid[m*512 + n];
        }
      }
    }
  }
}

// ---------------- v transpose: vb[b][k][d] bf16 -> vt tile-major [b][kt32][d(512)][k(32)]
__global__ __launch_bounds__(256) void vtrans_kernel(
    const unsigned short* __restrict__ vb, unsigned short* __restrict__ vt)
{
  __shared__ short T[64][72];
  int kt64 = blockIdx.x, dt = blockIdx.y, b = blockIdx.z;
  int tid = threadIdx.x;
#pragma unroll
  for (int i=0;i<4;++i){
    int c = tid + i*256; int r = c>>4, cc = (c&15)*4;
    *(ushort4*)&T[r][cc] = *(const ushort4*)&vb[(size_t)(b*2048 + kt64*64 + r)*512 + dt*64 + cc];
  }
  __syncthreads();
#pragma unroll
  for (int i=0;i<4;++i){
    int c = tid + i*256; int o = c*4;
    int ktl = o>>11, dl = (o>>5)&63, kk = o&31;
    ushort4 pk;
    pk.x = (unsigned short)T[ktl*32 + kk + 0][dl];
    pk.y = (unsigned short)T[ktl*32 + kk + 1][dl];
    pk.z = (unsigned short)T[ktl*32 + kk + 2][dl];
    pk.w = (unsigned short)T[ktl*32 + kk + 3][dl];
    *(ushort4*)&vt[((size_t)((b*64 + kt64*2 + ktl)*512) + dt*64 + dl)*32 + kk] = pk;
  }
}

// ---------------- flash attention + residual.
// grid 512: (b, 32-row q-tile, half of heads). 256 thr = 4 waves = 4 heads.
__global__ __launch_bounds__(256,2) void attn_kernel(
    const unsigned short* __restrict__ qb, const unsigned short* __restrict__ kb,
    const unsigned short* __restrict__ vt, const int* __restrict__ mask,
    const float* __restrict__ temp, float* __restrict__ O)
{
  const float RS2 = 0.044194173824159216f * 1.4426950408889634f; // 1/sqrt(512)*log2e
  int bid = blockIdx.x;
  int wg = (bid & 7)*64 + (bid >> 3);     // XCD-chunked swizzle (512 % 8 == 0)
  int b  = wg >> 7;
  int qt = (wg & 127) >> 1;
  int hv = wg & 1;                        // which half of the heads/channels
  int q0 = qt * 32;

  __shared__ short Ks[32][264];           // K rows, 256-ch slice, pad->stride 132w (opt 4-way)
  __shared__ short Vs[256][40];           // V^T rows [d][k], stride 20w
  __shared__ float BiasF[64*20];          // mask bias in C-frag layout, stride 20w
  __shared__ short Ps[4][32][40];         // per-wave P tile [q][k]

  int tid = threadIdx.x;
  int lane = tid & 63, w = tid >> 6, l5 = lane & 31, hi = lane >> 5;

  bf16x8 qf0, qf1, qf2, qf3;              // Q fragments (B-operand of S^T), hoisted
  {
    const unsigned short* qp = qb + (size_t)(b*2048 + q0 + l5)*512 + (hv*4 + w)*64 + hi*8;
    qf0 = *(const bf16x8*)(qp);
    qf1 = *(const bf16x8*)(qp + 16);
    qf2 = *(const bf16x8*)(qp + 32);
    qf3 = *(const bf16x8*)(qp + 48);
  }

  f32x16 o0, o1;
#pragma unroll
  for (int i=0;i<16;++i){ o0[i]=0.f; o1[i]=0.f; }
  float lsum = 0.f;

  for (int kt=0; kt<64; ++kt){
    int k0 = kt*32;
    __syncthreads();
    // stage K (32 rows x 256 ch of this half)
#pragma unroll
    for (int i=0;i<4;++i){
      int c = tid + i*256; int r = c>>5, j = c&31;
      *(uint4*)&Ks[r][j*8] = *(const uint4*)&kb[(size_t)(b*2048 + k0 + r)*512 + hv*256 + j*8];
    }
    // stage V^T (contiguous tile-major source)
    const unsigned short* vbase = vt + ((size_t)(b*64 + kt)*512 + hv*256)*32;
#pragma unroll
    for (int i=0;i<4;++i){
      int c = tid + i*256;
      *(uint4*)&Vs[c>>2][(c&3)*8] = *(const uint4*)&vbase[c*8];
    }
    // stage mask bias directly in C-fragment layout (shared by all 4 waves)
#pragma unroll
    for (int i=0;i<4;++i){
      int qq = (tid>>5) + i*8; int kk = tid & 31;
      int m = mask[(size_t)(b*2048 + q0 + qq)*2048 + k0 + kk];
      BiasF[(qq + ((kk>>2)&1)*32)*20 + (kk&3) + ((kk>>3)<<2)] = m ? 0.f : -1.44269504e9f;
    }
    __syncthreads();

    // S^T = K_tile @ Q_tile^T  (C: col=q fixed per lane, rows=k)
    f32x16 sA;
#pragma unroll
    for (int i=0;i<16;++i) sA[i] = 0.f;
    {
      bf16x8 kf;
      kf = *(const bf16x8*)&Ks[l5][w*64 +  0 + hi*8]; sA = MFMA32(kf, qf0, sA, 0,0,0);
      kf = *(const bf16x8*)&Ks[l5][w*64 + 16 + hi*8]; sA = MFMA32(kf, qf1, sA, 0,0,0);
      kf = *(const bf16x8*)&Ks[l5][w*64 + 32 + hi*8]; sA = MFMA32(kf, qf2, sA, 0,0,0);
      kf = *(const bf16x8*)&Ks[l5][w*64 + 48 + hi*8]; sA = MFMA32(kf, qf3, sA, 0,0,0);
    }
    // p = exp2(s * RS2/temp[k] + bias2); write P tile; accumulate row-sum
#pragma unroll
    for (int rq=0; rq<4; ++rq){
      float4 tq = *(const float4*)&temp[(size_t)b*2048 + k0 + rq*8 + hi*4];
      float4 bq = *(const float4*)&BiasF[lane*20 + rq*4];
      float p0 = exp2f(fmaf(sA[rq*4+0], RS2*__builtin_amdgcn_rcpf(tq.x), bq.x));
      float p1 = exp2f(fmaf(sA[rq*4+1], RS2*__builtin_amdgcn_rcpf(tq.y), bq.y));
      float p2 = exp2f(fmaf(sA[rq*4+2], RS2*__builtin_amdgcn_rcpf(tq.z), bq.z));
      float p3 = exp2f(fmaf(sA[rq*4+3], RS2*__builtin_amdgcn_rcpf(tq.w), bq.w));
      lsum += (p0 + p1) + (p2 + p3);
      uint2 uu; uu.x = bfpack2(p0, p1); uu.y = bfpack2(p2, p3);
      *(uint2*)&Ps[w][l5][rq*8 + hi*4] = uu;
    }
    // PV: A = P rows (LDS round-trip), B = V^T rows
    bf16x8 pa0 = *(const bf16x8*)&Ps[w][l5][hi*8];
    bf16x8 pa1 = *(const bf16x8*)&Ps[w][l5][16 + hi*8];
    bf16x8 v00 = *(const bf16x8*)&Vs[w*64      + l5][hi*8];
    bf16x8 v01 = *(const bf16x8*)&Vs[w*64      + l5][16 + hi*8];
    bf16x8 v10 = *(const bf16x8*)&Vs[w*64 + 32 + l5][hi*8];
    bf16x8 v11 = *(const bf16x8*)&Vs[w*64 + 32 + l5][16 + hi*8];
    o0 = MFMA32(pa0, v00, o0, 0,0,0);
    o0 = MFMA32(pa1, v01, o0, 0,0,0);
    o1 = MFMA32(pa0, v10, o1, 0,0,0);
    o1 = MFMA32(pa1, v11, o1, 0,0,0);
  }

  float lfull = lsum + __shfl_xor(lsum, 32, 64);
#pragma unroll
  for (int nt=0; nt<2; ++nt){
#pragma unroll
    for (int r=0;r<16;++r){
      int qlocal = (r&3) + 8*(r>>2) + 4*hi;
      float lq = __shfl(lfull, qlocal, 64);
      float inv = __builtin_amdgcn_rcpf(lq);
      int q = q0 + qlocal;
      int d = hv*256 + w*64 + nt*32 + l5;
      size_t idx = (size_t)(b*2048 + q)*512 + d;
      O[idx] = (nt==0 ? o0[r] : o1[r]) * inv + bf2f(qb[idx]);
    }
  }
}

// ---------------- LayerNorm over 512, 4 rows/block (one per wave)
__global__ __launch_bounds__(256) void ln_kernel(
    const float* __restrict__ X, const float* __restrict__ g,
    const float* __restrict__ be, float* __restrict__ Y)
{
  int row = blockIdx.x*4 + (threadIdx.x >> 6);
  int lane = threadIdx.x & 63;
  const float* x = X + (size_t)row*512 + lane*8;
  float4 v0 = *(const float4*)x;
  float4 v1 = *(const float4*)(x + 4);
  float s = ((v0.x+v0.y)+(v0.z+v0.w)) + ((v1.x+v1.y)+(v1.z+v1.w));
#pragma unroll
  for (int m=1; m<64; m<<=1) s += __shfl_xor(s, m, 64);
  float mean = s * (1.0f/512.0f);
  float d0=v0.x-mean, d1=v0.y-mean, d2=v0.z-mean, d3=v0.w-mean;
  float d4=v1.x-mean, d5=v1.y-mean, d6=v1.z-mean, d7=v1.w-mean;
  float s2 = ((d0*d0+d1*d1)+(d2*d2+d3*d3)) + ((d4*d4+d5*d5)+(d6*d6+d7*d7));
#pragma unroll
  for (int m=1; m<64; m<<=1) s2 += __shfl_xor(s2, m, 64);
  float rstd = rsqrtf(s2*(1.0f/512.0f) + 1e-5f);
  const float* gp = g + lane*8; const float* bp = be + lane*8;
  float4 g0 = *(const float4*)gp, g1 = *(const float4*)(gp+4);
  float4 b0 = *(const float4*)bp, b1 = *(const float4*)(bp+4);
  float4 y0, y1;
  y0.x = d0*rstd*g0.x + b0.x; y0.y = d1*rstd*g0.y + b0.y;
  y0.z = d2*rstd*g0.z + b0.z; y0.w = d3*rstd*g0.w + b0.w;
  y1.x = d4*rstd*g1.x + b1.x; y1.y = d5*rstd*g1.y + b1.y;
  y1.z = d6*rstd*g1.z + b1.z; y1.w = d7*rstd*g1.w + b1.w;
  float* yp = Y + (size_t)row*512 + lane*8;
  *(float4*)yp = y0;
  *(float4*)(yp+4) = y1;
}

extern "C" void kernel_launch(void* const* d_in, const int* in_sizes, int n_in,
                              void* d_out, int out_size, void* d_ws, size_t ws_size,
                              hipStream_t stream) {
  const float* Q    = (const float*)d_in[0];
  const float* K    = (const float*)d_in[1];
  const int*   mask = (const int*)d_in[2];
  const float* temp = (const float*)d_in[3];
  const float* Wq = (const float*)d_in[4];  const float* bq = (const float*)d_in[5];
  const float* Wk = (const float*)d_in[6];  const float* bk = (const float*)d_in[7];
  const float* Wv = (const float*)d_in[8];  const float* bv = (const float*)d_in[9];
  const float* Wo = (const float*)d_in[10]; const float* bo = (const float*)d_in[11];
  const float* g0 = (const float*)d_in[12]; const float* b0 = (const float*)d_in[13];
  const float* g1 = (const float*)d_in[14]; const float* b1 = (const float*)d_in[15];
  float* out = (float*)d_out;
  (void)in_sizes; (void)n_in; (void)out_size; (void)ws_size;

  char* ws = (char*)d_ws;
  unsigned short* qbuf = (unsigned short*)(ws + 0);          // 8.4MB  q proj (bf16)
  unsigned short* kbuf = (unsigned short*)(ws + 8388608);    // 8.4MB  k proj
  unsigned short* vbuf = (unsigned short*)(ws + 16777216);   // 8.4MB  v proj
  unsigned short* vtb  = (unsigned short*)(ws + 25165824);   // 8.4MB  v transposed tile-major
  unsigned short* WqT  = (unsigned short*)(ws + 33554432);   // 4 x 0.5MB
  unsigned short* WkT  = WqT + 262144;
  unsigned short* WvT  = WqT + 524288;
  unsigned short* WoT  = WqT + 786432;
  float* Obuf = (float*)(ws + 35651584);                     // 16.8MB attn out (pre-LN0)
  float* Olnf = (float*)(ws + 0);                            // aliases q/k bufs (dead post-attn)
  float* O2   = Obuf;                                        // aliases Obuf (dead post-LN0)

  wt_kernel<<<dim3(8,8,4), 256, 0, stream>>>(Wq, Wk, Wv, Wo, WqT, WkT, WvT, WoT);
  gemm_bt<0><<<dim3(64,4), 256, 0, stream>>>(Q, WqT, bq, (void*)qbuf, nullptr);
  gemm_bt<0><<<dim3(64,4), 256, 0, stream>>>(K, WkT, bk, (void*)kbuf, nullptr);
  gemm_bt<0><<<dim3(64,4), 256, 0, stream>>>(K, WvT, bv, (void*)vbuf, nullptr);
  vtrans_kernel<<<dim3(32,8,4), 256, 0, stream>>>(vbuf, vtb);
  attn_kernel<<<512, 256, 0, stream>>>(qbuf, kbuf, vtb, mask, temp, Obuf);
  ln_kernel<<<2048, 256, 0, stream>>>(Obuf, g0, b0, Olnf);
  gemm_bt<1><<<dim3(64,4), 256, 0, stream>>>(Olnf, WoT, bo, (void*)O2, Olnf);
  ln_kernel<<<2048, 256, 0, stream>>>(O2, g1, b1, out);
}

// Round 2
// 249.385 us; speedup vs baseline: 1.0490x; 1.0490x over previous
//
#include <hip/hip_runtime.h>

typedef __attribute__((ext_vector_type(8))) short bf16x8;
typedef __attribute__((ext_vector_type(16))) float f32x16;

#define MFMA32 __builtin_amdgcn_mfma_f32_32x32x16_bf16

__device__ __forceinline__ unsigned short bf16r(float f){
  unsigned u = __builtin_bit_cast(unsigned, f);
  unsigned r = (u + 0x7FFFu + ((u >> 16) & 1u)) >> 16;
  return (unsigned short)r;
}
__device__ __forceinline__ unsigned bfpack2(float a, float b){
  unsigned ua = __builtin_bit_cast(unsigned, a);
  unsigned ub = __builtin_bit_cast(unsigned, b);
  unsigned ra = (ua + 0x7FFFu + ((ua >> 16) & 1u)) >> 16;
  unsigned rb = (ub + 0x7FFFu + ((ub >> 16) & 1u)) & 0xFFFF0000u;
  return (ra & 0xFFFFu) | rb;
}
__device__ __forceinline__ float bf2f(unsigned short h){
  unsigned u = ((unsigned)h) << 16;
  return __builtin_bit_cast(float, u);
}

// ---------------- weight transpose: W[k][n] f32 -> WT[n][k] bf16 (512x512, 4 mats)
__global__ __launch_bounds__(256) void wt_kernel(
    const float* __restrict__ W0, const float* __restrict__ W1,
    const float* __restrict__ W2, const float* __restrict__ W3,
    unsigned short* __restrict__ T0, unsigned short* __restrict__ T1,
    unsigned short* __restrict__ T2, unsigned short* __restrict__ T3)
{
  int z = blockIdx.z;
  const float* W = z==0?W0 : z==1?W1 : z==2?W2 : W3;
  unsigned short* T = z==0?T0 : z==1?T1 : z==2?T2 : T3;
  __shared__ float tile[64][68];
  int kb0 = blockIdx.x*64, nb0 = blockIdx.y*64;
  int tid = threadIdx.x;
#pragma unroll
  for (int i=0;i<4;++i){
    int c = tid + i*256; int r = c>>4, cc = (c&15)*4;
    *(float4*)&tile[r][cc] = *(const float4*)&W[(kb0+r)*512 + nb0 + cc];
  }
  __syncthreads();
#pragma unroll
  for (int i=0;i<4;++i){
    int c = tid + i*256; int o = c*4; int n = o>>6, kk = o&63;
    ushort4 pk;
    pk.x = bf16r(tile[kk+0][n]); pk.y = bf16r(tile[kk+1][n]);
    pk.z = bf16r(tile[kk+2][n]); pk.w = bf16r(tile[kk+3][n]);
    *(ushort4*)&T[(nb0+n)*512 + kb0 + kk] = pk;
  }
}

// ---------------- scale precompute: scb[b][k] = log2e / (sqrt(512) * temp)
__global__ __launch_bounds__(256) void scale_kernel(
    const float* __restrict__ temp, float* __restrict__ scb)
{
  const float RS2 = 0.044194173824159216f * 1.4426950408889634f;
  int i = blockIdx.x*256 + threadIdx.x;
  scb[i] = RS2 / temp[i];
}

// ---------------- GEMM: C[m][n] = A(f32,[M x 512]) @ W via BT(bf16,[n][k]) + bias
// EPI 0: store bf16.  EPI 1: store f32 = relu(acc+bias) + resid.
template<int EPI>
__global__ __launch_bounds__(256,2) void gemm_bt(
    const float* __restrict__ A, const unsigned short* __restrict__ BT,
    const float* __restrict__ bias, void* __restrict__ Cout,
    const float* __restrict__ resid)
{
  __shared__ short As[128][72];
  __shared__ short Bs[128][72];
  int m0 = blockIdx.x*128, n0 = blockIdx.y*128;
  int tid = threadIdx.x;
  int lane = tid & 63, w = tid >> 6, l5 = lane & 31, hi = lane >> 5;
  int wr = w >> 1, wc = w & 1;
  f32x16 acc00, acc01, acc10, acc11;
#pragma unroll
  for (int i=0;i<16;++i){ acc00[i]=0.f; acc01[i]=0.f; acc10[i]=0.f; acc11[i]=0.f; }

  for (int kt=0; kt<8; ++kt){
    int k0 = kt*64;
    __syncthreads();
#pragma unroll
    for (int i=0;i<4;++i){
      int c = tid + i*256; int r = c>>3, cc = (c&7)*8;
      const float* src = &A[(m0+r)*512 + k0 + cc];
      float4 v0 = *(const float4*)src;
      float4 v1 = *(const float4*)(src+4);
      uint4 pk;
      pk.x = bfpack2(v0.x, v0.y); pk.y = bfpack2(v0.z, v0.w);
      pk.z = bfpack2(v1.x, v1.y); pk.w = bfpack2(v1.z, v1.w);
      *(uint4*)&As[r][cc] = pk;
    }
#pragma unroll
    for (int i=0;i<4;++i){
      int c = tid + i*256; int r = c>>3, cc = (c&7)*8;
      *(uint4*)&Bs[r][cc] = *(const uint4*)&BT[(n0+r)*512 + k0 + cc];
    }
    __syncthreads();
#pragma unroll
    for (int ks=0; ks<4; ++ks){
      bf16x8 a0 = *(const bf16x8*)&As[wr*64 + l5     ][ks*16 + hi*8];
      bf16x8 a1 = *(const bf16x8*)&As[wr*64 + 32 + l5][ks*16 + hi*8];
      bf16x8 b0 = *(const bf16x8*)&Bs[wc*64 + l5     ][ks*16 + hi*8];
      bf16x8 b1 = *(const bf16x8*)&Bs[wc*64 + 32 + l5][ks*16 + hi*8];
      acc00 = MFMA32(a0, b0, acc00, 0,0,0);
      acc01 = MFMA32(a0, b1, acc01, 0,0,0);
      acc10 = MFMA32(a1, b0, acc10, 0,0,0);
      acc11 = MFMA32(a1, b1, acc11, 0,0,0);
    }
  }
#pragma unroll
  for (int mt=0; mt<2; ++mt){
#pragma unroll
    for (int nt=0; nt<2; ++nt){
      const f32x16& acc = mt==0 ? (nt==0?acc00:acc01) : (nt==0?acc10:acc11);
      int n = n0 + wc*64 + nt*32 + l5;
      float bn = bias[n];
#pragma unroll
      for (int r=0;r<16;++r){
        int m = m0 + wr*64 + mt*32 + (r&3) + 8*(r>>2) + 4*hi;
        float v = acc[r] + bn;
        if (EPI==0){
          ((unsigned short*)Cout)[m*512 + n] = bf16r(v);
        } else {
          ((float*)Cout)[m*512 + n] = fmaxf(v, 0.f) + resid[m*512 + n];
        }
      }
    }
  }
}

// ---------------- v transpose: vb[b][k][d] bf16 -> vt tile-major [b][kt32][d(512)][k(32)]
__global__ __launch_bounds__(256) void vtrans_kernel(
    const unsigned short* __restrict__ vb, unsigned short* __restrict__ vt)
{
  __shared__ short T[64][72];
  int kt64 = blockIdx.x, dt = blockIdx.y, b = blockIdx.z;
  int tid = threadIdx.x;
#pragma unroll
  for (int i=0;i<4;++i){
    int c = tid + i*256; int r = c>>4, cc = (c&15)*4;
    *(ushort4*)&T[r][cc] = *(const ushort4*)&vb[(size_t)(b*2048 + kt64*64 + r)*512 + dt*64 + cc];
  }
  __syncthreads();
#pragma unroll
  for (int i=0;i<4;++i){
    int c = tid + i*256; int o = c*4;
    int ktl = o>>11, dl = (o>>5)&63, kk = o&31;
    ushort4 pk;
    pk.x = (unsigned short)T[ktl*32 + kk + 0][dl];
    pk.y = (unsigned short)T[ktl*32 + kk + 1][dl];
    pk.z = (unsigned short)T[ktl*32 + kk + 2][dl];
    pk.w = (unsigned short)T[ktl*32 + kk + 3][dl];
    *(ushort4*)&vt[((size_t)((b*64 + kt64*2 + ktl)*512) + dt*64 + dl)*32 + kk] = pk;
  }
}

// ---------------- flash attention, k-split x2, bf16 partials (no divide/residual here).
// grid 1024: (b, 32-row q-tile, half of heads, k-split). 256 thr = 4 waves = 4 heads.
__global__ __launch_bounds__(256,2) void attn_kernel(
    const unsigned short* __restrict__ qb, const unsigned short* __restrict__ kb,
    const unsigned short* __restrict__ vt, const int* __restrict__ mask,
    const float* __restrict__ scb, unsigned short* __restrict__ Op,
    float* __restrict__ lbuf)
{
  int bid = blockIdx.x;
  int swz = (bid & 7)*128 + (bid >> 3);   // XCD-chunked swizzle (1024 % 8 == 0)
  int s  = swz & 1;                       // k-split half
  int hv = (swz >> 1) & 1;                // which half of the heads/channels
  int qt = (swz >> 2) & 63;
  int b  = swz >> 8;
  int q0 = qt * 32;

  __shared__ short Ks[32][264];           // K rows, 256-ch slice, stride 132w (opt 4-way)
  __shared__ short Vs[256][40];           // V^T rows [d][k], stride 20w
  __shared__ float BiasF[64*20];          // mask bias in C-frag layout, stride 20w
  __shared__ short Ps[4][32][40];         // per-wave P tile [q][k]

  int tid = threadIdx.x;
  int lane = tid & 63, w = tid >> 6, l5 = lane & 31, hi = lane >> 5;

  bf16x8 qf0, qf1, qf2, qf3;              // Q fragments (B-operand of S^T), hoisted
  {
    const unsigned short* qp = qb + (size_t)(b*2048 + q0 + l5)*512 + (hv*4 + w)*64 + hi*8;
    qf0 = *(const bf16x8*)(qp);
    qf1 = *(const bf16x8*)(qp + 16);
    qf2 = *(const bf16x8*)(qp + 32);
    qf3 = *(const bf16x8*)(qp + 48);
  }

  f32x16 o0, o1;
#pragma unroll
  for (int i=0;i<16;++i){ o0[i]=0.f; o1[i]=0.f; }
  float lsum = 0.f;

  for (int kt=s*32; kt<s*32+32; ++kt){
    int k0 = kt*32;
    __syncthreads();
    // stage K (32 rows x 256 ch of this half)
#pragma unroll
    for (int i=0;i<4;++i){
      int c = tid + i*256; int r = c>>5, j = c&31;
      *(uint4*)&Ks[r][j*8] = *(const uint4*)&kb[(size_t)(b*2048 + k0 + r)*512 + hv*256 + j*8];
    }
    // stage V^T (contiguous tile-major source)
    const unsigned short* vbase = vt + ((size_t)(b*64 + kt)*512 + hv*256)*32;
#pragma unroll
    for (int i=0;i<4;++i){
      int c = tid + i*256;
      *(uint4*)&Vs[c>>2][(c&3)*8] = *(const uint4*)&vbase[c*8];
    }
    // stage mask bias (one int4 per thread) directly into C-fragment layout
    {
      int qq = tid >> 3, kk4 = tid & 7;
      int4 mv = *(const int4*)&mask[(size_t)(b*2048 + q0 + qq)*2048 + k0 + kk4*4];
      float4 bw;
      bw.x = mv.x ? 0.f : -1.44269504e9f;
      bw.y = mv.y ? 0.f : -1.44269504e9f;
      bw.z = mv.z ? 0.f : -1.44269504e9f;
      bw.w = mv.w ? 0.f : -1.44269504e9f;
      *(float4*)&BiasF[(qq + (kk4&1)*32)*20 + ((kk4>>1)<<2)] = bw;
    }
    __syncthreads();

    // S^T = K_tile @ Q_tile^T  (C: col=q fixed per lane, rows=k)
    f32x16 sA;
#pragma unroll
    for (int i=0;i<16;++i) sA[i] = 0.f;
    {
      bf16x8 kf;
      kf = *(const bf16x8*)&Ks[l5][w*64 +  0 + hi*8]; sA = MFMA32(kf, qf0, sA, 0,0,0);
      kf = *(const bf16x8*)&Ks[l5][w*64 + 16 + hi*8]; sA = MFMA32(kf, qf1, sA, 0,0,0);
      kf = *(const bf16x8*)&Ks[l5][w*64 + 32 + hi*8]; sA = MFMA32(kf, qf2, sA, 0,0,0);
      kf = *(const bf16x8*)&Ks[l5][w*64 + 48 + hi*8]; sA = MFMA32(kf, qf3, sA, 0,0,0);
    }
    // p = exp2(s * scale[k] + bias); write P tile; accumulate row-sum
#pragma unroll
    for (int rq=0; rq<4; ++rq){
      float4 sc4 = *(const float4*)&scb[(size_t)b*2048 + k0 + rq*8 + hi*4];
      float4 bq4 = *(const float4*)&BiasF[lane*20 + rq*4];
      float p0 = exp2f(fmaf(sA[rq*4+0], sc4.x, bq4.x));
      float p1 = exp2f(fmaf(sA[rq*4+1], sc4.y, bq4.y));
      float p2 = exp2f(fmaf(sA[rq*4+2], sc4.z, bq4.z));
      float p3 = exp2f(fmaf(sA[rq*4+3], sc4.w, bq4.w));
      lsum += (p0 + p1) + (p2 + p3);
      uint2 uu; uu.x = bfpack2(p0, p1); uu.y = bfpack2(p2, p3);
      *(uint2*)&Ps[w][l5][rq*8 + hi*4] = uu;
    }
    // PV: A = P rows (LDS round-trip), B = V^T rows
    bf16x8 pa0 = *(const bf16x8*)&Ps[w][l5][hi*8];
    bf16x8 pa1 = *(const bf16x8*)&Ps[w][l5][16 + hi*8];
    bf16x8 v00 = *(const bf16x8*)&Vs[w*64      + l5][hi*8];
    bf16x8 v01 = *(const bf16x8*)&Vs[w*64      + l5][16 + hi*8];
    bf16x8 v10 = *(const bf16x8*)&Vs[w*64 + 32 + l5][hi*8];
    bf16x8 v11 = *(const bf16x8*)&Vs[w*64 + 32 + l5][16 + hi*8];
    o0 = MFMA32(pa0, v00, o0, 0,0,0);
    o0 = MFMA32(pa1, v01, o0, 0,0,0);
    o1 = MFMA32(pa0, v10, o1, 0,0,0);
    o1 = MFMA32(pa1, v11, o1, 0,0,0);
  }

  float lfull = lsum + __shfl_xor(lsum, 32, 64);
  if (hi == 0){
    lbuf[(size_t)(b*2048 + q0 + l5)*16 + s*8 + (hv*4 + w)] = lfull;
  }
  unsigned short* op = Op + (size_t)s * 4194304u;
#pragma unroll
  for (int nt=0; nt<2; ++nt){
#pragma unroll
    for (int r=0;r<16;++r){
      int qlocal = (r&3) + 8*(r>>2) + 4*hi;
      int q = q0 + qlocal;
      int d = hv*256 + w*64 + nt*32 + l5;
      op[(size_t)(b*2048 + q)*512 + d] = bf16r(nt==0 ? o0[r] : o1[r]);
    }
  }
}

// ---------------- combine partials + divide + residual + LayerNorm0 (fused)
__global__ __launch_bounds__(256) void combine_ln_kernel(
    const unsigned short* __restrict__ OpA, const unsigned short* __restrict__ OpB,
    const float* __restrict__ lbuf, const unsigned short* __restrict__ qb,
    const float* __restrict__ g, const float* __restrict__ be, float* __restrict__ Y)
{
  int row = blockIdx.x*4 + (threadIdx.x >> 6);
  int lane = threadIdx.x & 63;
  int h = lane >> 3;
  float lA = lbuf[(size_t)row*16 + h];
  float lB = lbuf[(size_t)row*16 + 8 + h];
  float inv = __builtin_amdgcn_rcpf(lA + lB);
  size_t base = (size_t)row*512 + lane*8;
  bf16x8 a  = *(const bf16x8*)&OpA[base];
  bf16x8 bb = *(const bf16x8*)&OpB[base];
  bf16x8 qv = *(const bf16x8*)&qb[base];
  float x0 = (bf2f((unsigned short)a[0]) + bf2f((unsigned short)bb[0]))*inv + bf2f((unsigned short)qv[0]);
  float x1 = (bf2f((unsigned short)a[1]) + bf2f((unsigned short)bb[1]))*inv + bf2f((unsigned short)qv[1]);
  float x2 = (bf2f((unsigned short)a[2]) + bf2f((unsigned short)bb[2]))*inv + bf2f((unsigned short)qv[2]);
  float x3 = (bf2f((unsigned short)a[3]) + bf2f((unsigned short)bb[3]))*inv + bf2f((unsigned short)qv[3]);
  float x4 = (bf2f((unsigned short)a[4]) + bf2f((unsigned short)bb[4]))*inv + bf2f((unsigned short)qv[4]);
  float x5 = (bf2f((unsigned short)a[5]) + bf2f((unsigned short)bb[5]))*inv + bf2f((unsigned short)qv[5]);
  float x6 = (bf2f((unsigned short)a[6]) + bf2f((unsigned short)bb[6]))*inv + bf2f((unsigned short)qv[6]);
  float x7 = (bf2f((unsigned short)a[7]) + bf2f((unsigned short)bb[7]))*inv + bf2f((unsigned short)qv[7]);
  float sm = ((x0+x1)+(x2+x3)) + ((x4+x5)+(x6+x7));
#pragma unroll
  for (int m=1; m<64; m<<=1) sm += __shfl_xor(sm, m, 64);
  float mean = sm * (1.0f/512.0f);
  float d0=x0-mean, d1=x1-mean, d2=x2-mean, d3=x3-mean;
  float d4=x4-mean, d5=x5-mean, d6=x6-mean, d7=x7-mean;
  float s2 = ((d0*d0+d1*d1)+(d2*d2+d3*d3)) + ((d4*d4+d5*d5)+(d6*d6+d7*d7));
#pragma unroll
  for (int m=1; m<64; m<<=1) s2 += __shfl_xor(s2, m, 64);
  float rstd = rsqrtf(s2*(1.0f/512.0f) + 1e-5f);
  const float* gp = g + lane*8; const float* bp = be + lane*8;
  float4 g0 = *(const float4*)gp, g1 = *(const float4*)(gp+4);
  float4 b0 = *(const float4*)bp, b1 = *(const float4*)(bp+4);
  float4 y0, y1;
  y0.x = d0*rstd*g0.x + b0.x; y0.y = d1*rstd*g0.y + b0.y;
  y0.z = d2*rstd*g0.z + b0.z; y0.w = d3*rstd*g0.w + b0.w;
  y1.x = d4*rstd*g1.x + b1.x; y1.y = d5*rstd*g1.y + b1.y;
  y1.z = d6*rstd*g1.z + b1.z; y1.w = d7*rstd*g1.w + b1.w;
  float* yp = Y + base;
  *(float4*)yp = y0;
  *(float4*)(yp+4) = y1;
}

// ---------------- LayerNorm over 512, 4 rows/block (one per wave)
__global__ __launch_bounds__(256) void ln_kernel(
    const float* __restrict__ X, const float* __restrict__ g,
    const float* __restrict__ be, float* __restrict__ Y)
{
  int row = blockIdx.x*4 + (threadIdx.x >> 6);
  int lane = threadIdx.x & 63;
  const float* x = X + (size_t)row*512 + lane*8;
  float4 v0 = *(const float4*)x;
  float4 v1 = *(const float4*)(x + 4);
  float s = ((v0.x+v0.y)+(v0.z+v0.w)) + ((v1.x+v1.y)+(v1.z+v1.w));
#pragma unroll
  for (int m=1; m<64; m<<=1) s += __shfl_xor(s, m, 64);
  float mean = s * (1.0f/512.0f);
  float d0=v0.x-mean, d1=v0.y-mean, d2=v0.z-mean, d3=v0.w-mean;
  float d4=v1.x-mean, d5=v1.y-mean, d6=v1.z-mean, d7=v1.w-mean;
  float s2 = ((d0*d0+d1*d1)+(d2*d2+d3*d3)) + ((d4*d4+d5*d5)+(d6*d6+d7*d7));
#pragma unroll
  for (int m=1; m<64; m<<=1) s2 += __shfl_xor(s2, m, 64);
  float rstd = rsqrtf(s2*(1.0f/512.0f) + 1e-5f);
  const float* gp = g + lane*8; const float* bp = be + lane*8;
  float4 g0 = *(const float4*)gp, g1 = *(const float4*)(gp+4);
  float4 b0 = *(const float4*)bp, b1 = *(const float4*)(bp+4);
  float4 y0, y1;
  y0.x = d0*rstd*g0.x + b0.x; y0.y = d1*rstd*g0.y + b0.y;
  y0.z = d2*rstd*g0.z + b0.z; y0.w = d3*rstd*g0.w + b0.w;
  y1.x = d4*rstd*g1.x + b1.x; y1.y = d5*rstd*g1.y + b1.y;
  y1.z = d6*rstd*g1.z + b1.z; y1.w = d7*rstd*g1.w + b1.w;
  float* yp = Y + (size_t)row*512 + lane*8;
  *(float4*)yp = y0;
  *(float4*)(yp+4) = y1;
}

extern "C" void kernel_launch(void* const* d_in, const int* in_sizes, int n_in,
                              void* d_out, int out_size, void* d_ws, size_t ws_size,
                              hipStream_t stream) {
  const float* Q    = (const float*)d_in[0];
  const float* K    = (const float*)d_in[1];
  const int*   mask = (const int*)d_in[2];
  const float* temp = (const float*)d_in[3];
  const float* Wq = (const float*)d_in[4];  const float* bq = (const float*)d_in[5];
  const float* Wk = (const float*)d_in[6];  const float* bk = (const float*)d_in[7];
  const float* Wv = (const float*)d_in[8];  const float* bv = (const float*)d_in[9];
  const float* Wo = (const float*)d_in[10]; const float* bo = (const float*)d_in[11];
  const float* g0 = (const float*)d_in[12]; const float* b0 = (const float*)d_in[13];
  const float* g1 = (const float*)d_in[14]; const float* b1 = (const float*)d_in[15];
  float* out = (float*)d_out;
  (void)in_sizes; (void)n_in; (void)out_size; (void)ws_size;

  char* ws = (char*)d_ws;
  unsigned short* qbuf = (unsigned short*)(ws + 0);          // 8.4MB  q proj (bf16)
  unsigned short* kbuf = (unsigned short*)(ws + 8388608);    // 8.4MB  k proj
  unsigned short* vtb  = (unsigned short*)(ws + 16777216);   // 8.4MB  v transposed tile-major
  unsigned short* vbuf = (unsigned short*)(ws + 25165824);   // 8.4MB  v proj (dead after vtrans)
  unsigned short* OpA  = (unsigned short*)(ws + 25165824);   // 2x 8.4MB bf16 partials (alias vbuf)
  unsigned short* WqT  = (unsigned short*)(ws + 41943040);   // 4 x 0.5MB
  unsigned short* WkT  = WqT + 262144;
  unsigned short* WvT  = WqT + 524288;
  unsigned short* WoT  = WqT + 786432;
  float* lbuf = (float*)(ws + 44040192);                     // 512KB per-(row,split,head) sums
  float* scb  = (float*)(ws + 44564480);                     // 32KB scale
  float* Olnf = (float*)(ws + 8388608);                      // 16.8MB post-LN0 (alias kbuf+vtb)
  float* O2   = (float*)(ws + 25165824);                     // 16.8MB post-GEMM (alias partials)

  wt_kernel<<<dim3(8,8,4), 256, 0, stream>>>(Wq, Wk, Wv, Wo, WqT, WkT, WvT, WoT);
  scale_kernel<<<32, 256, 0, stream>>>(temp, scb);
  gemm_bt<0><<<dim3(64,4), 256, 0, stream>>>(Q, WqT, bq, (void*)qbuf, nullptr);
  gemm_bt<0><<<dim3(64,4), 256, 0, stream>>>(K, WkT, bk, (void*)kbuf, nullptr);
  gemm_bt<0><<<dim3(64,4), 256, 0, stream>>>(K, WvT, bv, (void*)vbuf, nullptr);
  vtrans_kernel<<<dim3(32,8,4), 256, 0, stream>>>(vbuf, vtb);
  attn_kernel<<<1024, 256, 0, stream>>>(qbuf, kbuf, vtb, mask, scb, OpA, lbuf);
  combine_ln_kernel<<<2048, 256, 0, stream>>>(OpA, OpA + 4194304, lbuf, qbuf, g0, b0, Olnf);
  gemm_bt<1><<<dim3(64,4), 256, 0, stream>>>(Olnf, WoT, bo, (void*)O2, Olnf);
  ln_kernel<<<2048, 256, 0, stream>>>(O2, g1, b1, out);
}